// Round 1
// 843.837 us; speedup vs baseline: 1.3015x; 1.3015x over previous
//
#include <hip/hip_runtime.h>

#define N_NODES 100000
#define N_EDGES 1600000
#define CAP 64   // max in-degree slots; P(Binom(1.6M,1e-5) >= 64) ~ 3e-22/node

typedef short short8 __attribute__((ext_vector_type(8)));
typedef float f32x4 __attribute__((ext_vector_type(4)));

__device__ __forceinline__ unsigned short f2b(float f) {
    unsigned u = __builtin_bit_cast(unsigned, f);
    u += 0x7fffu + ((u >> 16) & 1u);          // RNE
    return (unsigned short)(u >> 16);
}
__device__ __forceinline__ float b2f_lo(unsigned p) {
    return __builtin_bit_cast(float, p << 16);
}
__device__ __forceinline__ float b2f_hi(unsigned p) {
    return __builtin_bit_cast(float, p & 0xffff0000u);
}
__device__ __forceinline__ float b2f(unsigned short s) {
    return __builtin_bit_cast(float, ((unsigned)s) << 16);
}

// ---------------- fp32 -> bf16 bulk convert ----------------
__global__ void k_f2b(const float* __restrict__ in, unsigned short* __restrict__ out, int n4) {
    int i = blockIdx.x * blockDim.x + threadIdx.x;
    if (i < n4) {
        float4 v = ((const float4*)in)[i];
        uint2 o;
        o.x = (unsigned)f2b(v.x) | ((unsigned)f2b(v.y) << 16);
        o.y = (unsigned)f2b(v.z) | ((unsigned)f2b(v.w) << 16);
        ((uint2*)out)[i] = o;
    }
}

// ---------------- W[3*CIN][COUT] fp32 -> Wt[COUT][3*CIN] bf16 ----------------
__global__ void k_wt(const float* __restrict__ W, unsigned short* __restrict__ Wt,
                     int KT, int COUT) {
    int i = blockIdx.x * blockDim.x + threadIdx.x;
    if (i < KT * COUT) {
        int k = i % KT, n = i / KT;
        Wt[(size_t)n * KT + k] = f2b(W[(size_t)k * COUT + n]);
    }
}

// ---------------- fused degree-count + direct-slot CSR build ----------------
// degout[s] += 1 (float, for rsqrt); slots[d*CAP + pos] = s with atomic cursor cnt[d].
// Replaces k_degboth + k_scan + k_scatter: 2 atomics/edge total (was 3) and one
// edge-list pass (was 2); no prefix scan needed since addressing is fixed-stride.
__global__ void k_build(const int* __restrict__ src, const int* __restrict__ dst,
                        float* __restrict__ degout, int* __restrict__ cnt,
                        int* __restrict__ slots) {
    int e = blockIdx.x * blockDim.x + threadIdx.x;
    if (e < N_EDGES) {
        int s = src[e], d = dst[e];
        if (s != d) {
            atomicAdd(&degout[s], 1.0f);
            int pos = atomicAdd(&cnt[d], 1);
            if (pos < CAP) slots[(size_t)d * CAP + pos] = s;   // guard never fires in practice
        }
    }
}

__global__ void k_dinv(float* __restrict__ deg) {
    int n = blockIdx.x * blockDim.x + threadIdx.x;
    if (n < N_NODES) {
        float dg = deg[n];
        deg[n] = dg > 0.f ? rsqrtf(dg) : 0.f;
    }
}

// ---------------- gather v3: direct-slot CSR, on-the-fly weights ----------------
// out[n] = alpha * sum_e (-dinv[c]*dinv[n]) * h[c]  (+ beta*init[n])
//        = (-alpha*dinv[n]) * sum_e dinv[c]*h[c]    (+ beta*init[n])
// deg <= CAP=64 always -> single lane-batch, no outer chunk loop, no row-pointer read.
template <int C>
__global__ __launch_bounds__(256) void k_gather3(const unsigned short* __restrict__ h,
                                                 const int* __restrict__ cnt,
                                                 const int* __restrict__ slots,
                                                 const float* __restrict__ dinv,
                                                 float alpha, const unsigned short* __restrict__ init,
                                                 float beta, unsigned short* __restrict__ out) {
    const int wave = threadIdx.x >> 6;
    const int lane = threadIdx.x & 63;
    const int n = blockIdx.x * 4 + wave;
    if (n >= N_NODES) return;
    const int m = min(cnt[n], CAP);
    const float scale = -alpha * dinv[n];

    int col = 0;
    float w = 0.f;
    if (lane < m) {
        col = slots[(size_t)n * CAP + lane];
        w = dinv[col];                        // 400KB array, L2-resident
    }
    const int wi = __builtin_bit_cast(int, w);

    if (C == 128) {
        const unsigned* h2 = (const unsigned*)h;
        float ax = 0.f, ay = 0.f;
        int j = 0;
        for (; j + 4 <= m; j += 4) {
            int c0 = __builtin_amdgcn_readlane(col, j + 0);
            int c1 = __builtin_amdgcn_readlane(col, j + 1);
            int c2 = __builtin_amdgcn_readlane(col, j + 2);
            int c3 = __builtin_amdgcn_readlane(col, j + 3);
            float w0 = __builtin_bit_cast(float, __builtin_amdgcn_readlane(wi, j + 0));
            float w1 = __builtin_bit_cast(float, __builtin_amdgcn_readlane(wi, j + 1));
            float w2 = __builtin_bit_cast(float, __builtin_amdgcn_readlane(wi, j + 2));
            float w3 = __builtin_bit_cast(float, __builtin_amdgcn_readlane(wi, j + 3));
            unsigned q0 = h2[(size_t)c0 * 64 + lane];
            unsigned q1 = h2[(size_t)c1 * 64 + lane];
            unsigned q2 = h2[(size_t)c2 * 64 + lane];
            unsigned q3 = h2[(size_t)c3 * 64 + lane];
            ax = fmaf(w0, b2f_lo(q0), ax); ay = fmaf(w0, b2f_hi(q0), ay);
            ax = fmaf(w1, b2f_lo(q1), ax); ay = fmaf(w1, b2f_hi(q1), ay);
            ax = fmaf(w2, b2f_lo(q2), ax); ay = fmaf(w2, b2f_hi(q2), ay);
            ax = fmaf(w3, b2f_lo(q3), ax); ay = fmaf(w3, b2f_hi(q3), ay);
        }
        for (; j < m; j++) {
            int c0 = __builtin_amdgcn_readlane(col, j);
            float w0 = __builtin_bit_cast(float, __builtin_amdgcn_readlane(wi, j));
            unsigned q0 = h2[(size_t)c0 * 64 + lane];
            ax = fmaf(w0, b2f_lo(q0), ax); ay = fmaf(w0, b2f_hi(q0), ay);
        }
        float vx = scale * ax, vy = scale * ay;
        if (init) {
            unsigned ip = ((const unsigned*)init)[(size_t)n * 64 + lane];
            vx = fmaf(beta, b2f_lo(ip), vx);
            vy = fmaf(beta, b2f_hi(ip), vy);
        }
        ((unsigned*)out)[(size_t)n * 64 + lane] =
            (unsigned)f2b(vx) | ((unsigned)f2b(vy) << 16);
    } else {   // C == 64
        float a = 0.f;
        int j = 0;
        for (; j + 4 <= m; j += 4) {
            int c0 = __builtin_amdgcn_readlane(col, j + 0);
            int c1 = __builtin_amdgcn_readlane(col, j + 1);
            int c2 = __builtin_amdgcn_readlane(col, j + 2);
            int c3 = __builtin_amdgcn_readlane(col, j + 3);
            float w0 = __builtin_bit_cast(float, __builtin_amdgcn_readlane(wi, j + 0));
            float w1 = __builtin_bit_cast(float, __builtin_amdgcn_readlane(wi, j + 1));
            float w2 = __builtin_bit_cast(float, __builtin_amdgcn_readlane(wi, j + 2));
            float w3 = __builtin_bit_cast(float, __builtin_amdgcn_readlane(wi, j + 3));
            float v0 = b2f(h[(size_t)c0 * 64 + lane]);
            float v1 = b2f(h[(size_t)c1 * 64 + lane]);
            float v2 = b2f(h[(size_t)c2 * 64 + lane]);
            float v3 = b2f(h[(size_t)c3 * 64 + lane]);
            a = fmaf(w0, v0, a); a = fmaf(w1, v1, a);
            a = fmaf(w2, v2, a); a = fmaf(w3, v3, a);
        }
        for (; j < m; j++) {
            int c0 = __builtin_amdgcn_readlane(col, j);
            float w0 = __builtin_bit_cast(float, __builtin_amdgcn_readlane(wi, j));
            a = fmaf(w0, b2f(h[(size_t)c0 * 64 + lane]), a);
        }
        float v = scale * a;
        if (init) v = fmaf(beta, b2f(init[(size_t)n * 64 + lane]), v);
        out[(size_t)n * 64 + lane] = f2b(v);
    }
}

// ---------------- MFMA GEMM v2: LDS-staged Wt N-slice, 128-row blocks ----------------
// grid (ceil(N/128), COUT/NSL); block 256 (4 waves); wave w: rows w*32..w*32+31 (2 m-frags)
// LDS: Wt slice [NSL][KT] bf16, row padded +8 shorts -> <=2-way bank aliasing (free)
template <int CIN, int COUT, int NSL, bool RELU, bool BF16OUT>
__global__ __launch_bounds__(256) void k_mm2(const unsigned short* __restrict__ t0,
                                             const unsigned short* __restrict__ t1,
                                             const unsigned short* __restrict__ t2,
                                             const unsigned short* __restrict__ Wt,
                                             const float* __restrict__ bias,
                                             void* __restrict__ outv) {
    constexpr int KT = 3 * CIN;
    constexpr int KP = KT + 8;
    constexpr int NFR = NSL / 16;
    __shared__ unsigned short sw[NSL * KP];

    const int tid = threadIdx.x;
    const int n0 = blockIdx.y * NSL;

    // stage Wt[n0..n0+NSL)[0..KT) -> LDS (16B chunks, coalesced)
    constexpr int CHUNKS = NSL * KT / 8;
    for (int i = tid; i < CHUNKS; i += 256) {
        int row = i / (KT / 8);
        int k8 = i % (KT / 8);
        short8 v = *(const short8*)(Wt + (size_t)(n0 + row) * KT + k8 * 8);
        *(short8*)(sw + row * KP + k8 * 8) = v;
    }
    __syncthreads();

    const int wave = tid >> 6, lane = tid & 63;
    const int l16 = lane & 15, quad = lane >> 4;
    const int mBase = blockIdx.x * 128 + wave * 32;
    const int r0 = mBase + l16, r1 = mBase + 16 + l16;
    const bool in0 = r0 < N_NODES, in1 = r1 < N_NODES;

    f32x4 acc[2][NFR] = {};
    const unsigned short* tb[3] = {t0, t1, t2};
    const short8 zero8 = {0, 0, 0, 0, 0, 0, 0, 0};

    #pragma unroll
    for (int kt = 0; kt < KT / 32; kt++) {
        const int kb = kt * 32;
        const unsigned short* t = tb[kb / CIN];
        const int kin = (kb % CIN) + quad * 8;
        short8 a0 = zero8, a1 = zero8;
        if (in0) a0 = *(const short8*)(t + (size_t)r0 * CIN + kin);
        if (in1) a1 = *(const short8*)(t + (size_t)r1 * CIN + kin);
        #pragma unroll
        for (int nf = 0; nf < NFR; nf++) {
            const short8 b = *(const short8*)(sw + (nf * 16 + l16) * KP + kb + quad * 8);
            acc[0][nf] = __builtin_amdgcn_mfma_f32_16x16x32_bf16(a0, b, acc[0][nf], 0, 0, 0);
            acc[1][nf] = __builtin_amdgcn_mfma_f32_16x16x32_bf16(a1, b, acc[1][nf], 0, 0, 0);
        }
    }

    // C/D layout: col = lane&15, row = quad*4 + reg
    #pragma unroll
    for (int mi = 0; mi < 2; mi++) {
        #pragma unroll
        for (int nf = 0; nf < NFR; nf++) {
            #pragma unroll
            for (int r = 0; r < 4; r++) {
                const int node = mBase + mi * 16 + quad * 4 + r;
                if (node < N_NODES) {
                    const int co = n0 + nf * 16 + l16;
                    float o = acc[mi][nf][r] + bias[co];
                    if (RELU) o = fmaxf(o, 0.f);
                    if (BF16OUT)
                        ((unsigned short*)outv)[(size_t)node * COUT + co] = f2b(o);
                    else
                        ((float*)outv)[(size_t)node * COUT + co] = o;
                }
            }
        }
    }
}

// ---------------- launch ----------------
static inline int ceil_div(int a, int b) { return (a + b - 1) / b; }

extern "C" void kernel_launch(void* const* d_in, const int* in_sizes, int n_in,
                              void* d_out, int out_size, void* d_ws, size_t ws_size,
                              hipStream_t stream) {
    const float* x   = (const float*)d_in[0];
    const int*   ei  = (const int*)d_in[1];
    const int*   src = ei;
    const int*   dst = ei + N_EDGES;
    const float* W1 = (const float*)d_in[3];
    const float* b1 = (const float*)d_in[4];
    const float* W2 = (const float*)d_in[5];
    const float* b2 = (const float*)d_in[6];
    const float* W3 = (const float*)d_in[7];
    const float* b3 = (const float*)d_in[8];
    float* out = (float*)d_out;

    // workspace layout (8B-aligned first)
    char* p = (char*)d_ws;
    int*   slots  = (int*)p;             p += (size_t)N_NODES * CAP * 4;
    float* dinv   = (float*)p;           p += (size_t)N_NODES * 4;
    int*   cnt    = (int*)p;             p += (size_t)N_NODES * 4;
    unsigned short* xb   = (unsigned short*)p; p += (size_t)N_NODES * 128 * 2;
    unsigned short* tx1b = (unsigned short*)p; p += (size_t)N_NODES * 128 * 2;
    unsigned short* tx2b = (unsigned short*)p; p += (size_t)N_NODES * 128 * 2;
    unsigned short* h1b  = (unsigned short*)p; p += (size_t)N_NODES * 64 * 2;
    unsigned short* h2b  = (unsigned short*)p; p += (size_t)N_NODES * 128 * 2;
    unsigned short* Wt1  = (unsigned short*)p; p += (size_t)64 * 384 * 2;
    unsigned short* Wt2  = (unsigned short*)p; p += (size_t)128 * 192 * 2;
    unsigned short* Wt3  = (unsigned short*)p; p += (size_t)256 * 384 * 2;

    const int TB = 256;
    const int gE = ceil_div(N_EDGES, TB);
    const int gN = ceil_div(N_NODES, TB);
    const int gG = ceil_div(N_NODES, 4);     // gather: 4 nodes per 256-thr block
    const int gM = ceil_div(N_NODES, 128);   // mm2: 128 rows per block

    // conversions
    k_f2b<<<ceil_div(N_NODES * 128 / 4, TB), TB, 0, stream>>>(x, xb, N_NODES * 128 / 4);
    k_wt<<<ceil_div(384 * 64, TB), TB, 0, stream>>>(W1, Wt1, 384, 64);
    k_wt<<<ceil_div(192 * 128, TB), TB, 0, stream>>>(W2, Wt2, 192, 128);
    k_wt<<<ceil_div(384 * 256, TB), TB, 0, stream>>>(W3, Wt3, 384, 256);

    // fused degree + direct-slot CSR (replaces degboth/scan/scatter)
    hipMemsetAsync(dinv, 0, N_NODES * sizeof(float), stream);
    hipMemsetAsync(cnt, 0, N_NODES * sizeof(int), stream);
    k_build<<<gE, TB, 0, stream>>>(src, dst, dinv, cnt, slots);
    k_dinv<<<gN, TB, 0, stream>>>(dinv);

    // ---- layer 1: 128 -> 64, relu ----
    k_gather3<128><<<gG, TB, 0, stream>>>(xb, cnt, slots, dinv, 1.f, nullptr, 0.f, tx1b);
    k_gather3<128><<<gG, TB, 0, stream>>>(tx1b, cnt, slots, dinv, 2.f, xb, -1.f, tx2b);
    k_mm2<128, 64, 64, true, true><<<dim3(gM, 1), TB, 0, stream>>>(xb, tx1b, tx2b, Wt1, b1, h1b);

    // ---- layer 2: 64 -> 128, relu ----
    k_gather3<64><<<gG, TB, 0, stream>>>(h1b, cnt, slots, dinv, 1.f, nullptr, 0.f, tx1b);
    k_gather3<64><<<gG, TB, 0, stream>>>(tx1b, cnt, slots, dinv, 2.f, h1b, -1.f, tx2b);
    k_mm2<64, 128, 128, true, true><<<dim3(gM, 1), TB, 0, stream>>>(h1b, tx1b, tx2b, Wt2, b2, h2b);

    // ---- layer 3: 128 -> 256, no relu ----
    k_gather3<128><<<gG, TB, 0, stream>>>(h2b, cnt, slots, dinv, 1.f, nullptr, 0.f, tx1b);
    k_gather3<128><<<gG, TB, 0, stream>>>(tx1b, cnt, slots, dinv, 2.f, h2b, -1.f, tx2b);
    k_mm2<128, 256, 64, false, false><<<dim3(gM, 4), TB, 0, stream>>>(h2b, tx1b, tx2b, Wt3, b3, out);
}